// Round 8
// baseline (118.341 us; speedup 1.0000x reference)
//
#include <hip/hip_runtime.h>
#include <hip/hip_bf16.h>
#include <float.h>

// GraphSAGE: masked-max agg + ReLU + concat + Linear(256->128).
// B=4, N=512, C=128, OUT=128.
//
// R8: SINGLE dispatch. Grid = 2048 agg blocks + 256 gemm blocks.
//  - agg block (bid<2048): R7 aggregation (4 waves, quarter-row each,
//    8-wide padded gather rounds), writes bf16 comb row to ws, then
//    __threadfence() + atomic flag[node]=MAGIC (device scope, G16).
//  - gemm block (bid>=2048): spin-polls the 16 node flags for its mt
//    (atomicAdd+0 = device-scope RMW), fence, then 4 MFMA 16x16 tiles
//    (waves = nt (g&1)*4..+4, mt = g>>1). B-frag built from fp32 W on the
//    fly (R4 path; R7 showed bf16 Wt prep is neutral). A-frag b128 from comb.
// Deadlock-free: 256 waiting blocks << resident capacity; agg never waits.
// Flags in ws: poison 0xAAAAAAAA != MAGIC resets handshake every replay.
//
// Rationale: R7 tweaks were neutral -> kernels are near their ~3us floor;
// the controllable slice (~13us over the ~55us harness fill/restore floor)
// is mostly per-dispatch gap. This removes one of the two dispatches AND
// lets gemm overlap agg's tail per-node.

#define Bsz 4
#define Nn  512
#define Cc  128
#define OUTn 128
#define NNODES (Bsz * Nn)   // 2048
#define KK (2 * Cc)         // 256
#define GEMM_BLOCKS (NNODES / 16 * (OUTn / 16) / 4)   // 256
#define MAGIC 0x5EC7DA7Au

typedef __bf16 bf16x8 __attribute__((ext_vector_type(8)));
typedef float  f32x4  __attribute__((ext_vector_type(4)));

static __device__ __forceinline__ unsigned short f2bf(float x) {
    __hip_bfloat16 h = __float2bfloat16(x);
    return *reinterpret_cast<unsigned short*>(&h);
}
static __device__ __forceinline__ __bf16 f2bf16(float x) {
    unsigned short u = f2bf(x);
    return *reinterpret_cast<__bf16*>(&u);
}

__global__ __launch_bounds__(256) void sage_onepass(
    const float* __restrict__ adj,
    const float* __restrict__ feat,
    const float* __restrict__ W,          // fp32 [256][128]
    const float* __restrict__ bias,
    unsigned short* __restrict__ comb,    // ws: bf16 [2048][256]
    unsigned int* __restrict__ flags,     // ws: [2048]
    float* __restrict__ out)              // fp32 [2048][128]
{
    const int bid = blockIdx.x;

    if (bid < NNODES) {
        // ================= aggregation block =================
        const int w = threadIdx.x >> 6;
        const int l = threadIdx.x & 63;
        const int node = bid;
        const int b = node >> 9;
        const int i = node & (Nn - 1);

        __shared__ unsigned short nbr[4][128];
        __shared__ float2 pmax[4][64];

        const float* adjrow = adj + (size_t)node * Nn;
        const float2* f2 = (const float2*)(feat + (size_t)b * Nn * Cc);

        int cnt = 0;
        #pragma unroll
        for (int ch = 0; ch < 2; ++ch) {
            int j = w * 128 + ch * 64 + l;
            float a = adjrow[j];
            unsigned long long mask = __ballot(a > 0.0f);
            int pos = __popcll(mask & ((1ull << l) - 1ull));
            if (a > 0.0f) nbr[w][cnt + pos] = (unsigned short)j;
            cnt += __popcll(mask);
        }
        // Pad list to a multiple of 8 with a duplicate (max is idempotent).
        if (cnt > 0) {
            unsigned short p0 = nbr[w][0];
            int padded = (cnt + 7) & ~7;
            if (l < padded - cnt) nbr[w][cnt + l] = p0;
            cnt = padded;
        }

        float m0 = -FLT_MAX, m1 = -FLT_MAX;
        for (int k = 0; k < cnt; k += 8) {
            int j0 = nbr[w][k + 0], j1 = nbr[w][k + 1];
            int j2 = nbr[w][k + 2], j3 = nbr[w][k + 3];
            int j4 = nbr[w][k + 4], j5 = nbr[w][k + 5];
            int j6 = nbr[w][k + 6], j7 = nbr[w][k + 7];
            float2 v0 = f2[j0 * 64 + l];
            float2 v1 = f2[j1 * 64 + l];
            float2 v2 = f2[j2 * 64 + l];
            float2 v3 = f2[j3 * 64 + l];
            float2 v4 = f2[j4 * 64 + l];
            float2 v5 = f2[j5 * 64 + l];
            float2 v6 = f2[j6 * 64 + l];
            float2 v7 = f2[j7 * 64 + l];
            m0 = fmaxf(m0, fmaxf(fmaxf(fmaxf(v0.x, v1.x), fmaxf(v2.x, v3.x)),
                                 fmaxf(fmaxf(v4.x, v5.x), fmaxf(v6.x, v7.x))));
            m1 = fmaxf(m1, fmaxf(fmaxf(fmaxf(v0.y, v1.y), fmaxf(v2.y, v3.y)),
                                 fmaxf(fmaxf(v4.y, v5.y), fmaxf(v6.y, v7.y))));
        }
        pmax[w][l] = make_float2(m0, m1);
        __syncthreads();

        if (w == 0) {
            float2 p0 = pmax[0][l], p1 = pmax[1][l], p2 = pmax[2][l], p3 = pmax[3][l];
            float n0 = fmaxf(fmaxf(p0.x, p1.x), fmaxf(p2.x, p3.x));
            float n1 = fmaxf(fmaxf(p0.y, p1.y), fmaxf(p2.y, p3.y));
            // relu(max) maps no-neighbor (-FLT_MAX) to 0 == reference
            // (finfo.min is finite; its isfinite-guard never fires).
            n0 = fmaxf(n0, 0.0f);
            n1 = fmaxf(n1, 0.0f);
            float2 s = f2[i * 64 + l];

            ushort2* crow = (ushort2*)(comb + (size_t)node * KK);
            ushort2 sv; sv.x = f2bf(s.x); sv.y = f2bf(s.y);
            ushort2 nv; nv.x = f2bf(n0);  nv.y = f2bf(n1);
            crow[l]      = sv;   // self  ch [2l, 2l+1]
            crow[64 + l] = nv;   // neigh ch [128+2l, 128+2l+1]

            // Release: make comb row device-visible, then set the flag.
            __threadfence();
            if (l == 0) atomicExch(&flags[node], MAGIC);
        }
        return;
    }

    // ================= gemm block =================
    // g in [0,256); covers mt = g>>1, nt = (g&1)*4 + wave. 4 tiles/block.
    const int g = bid - NNODES;
    const int mt = g >> 1;

    // Acquire: wait for the 16 comb rows of this mt.
    if (threadIdx.x < 16) {
        unsigned int* f = &flags[mt * 16 + threadIdx.x];
        while (atomicAdd(f, 0u) != MAGIC) { }
        __threadfence();
    }
    __syncthreads();

    const int wave = threadIdx.x >> 6;
    const int lane = threadIdx.x & 63;
    const int nt = (g & 1) * 4 + wave;

    const int frow = lane & 15;
    const int koff = (lane >> 4) * 8;

    const __bf16* pa = (const __bf16*)comb + (size_t)(mt * 16 + frow) * KK + koff;
    const float*  wp = W + nt * 16 + frow;   // stride OUTn over k

    f32x4 acc = {0.f, 0.f, 0.f, 0.f};
    #pragma unroll
    for (int ks = 0; ks < KK / 32; ++ks) {
        bf16x8 af = *(const bf16x8*)(pa + ks * 32);
        bf16x8 bfr;
        #pragma unroll
        for (int j = 0; j < 8; ++j) {
            bfr[j] = f2bf16(wp[(size_t)(ks * 32 + koff + j) * OUTn]);
        }
        acc = __builtin_amdgcn_mfma_f32_16x16x32_bf16(af, bfr, acc, 0, 0, 0);
    }

    // C/D: col = lane&15, row = (lane>>4)*4 + reg  [measured m89/m91]
    const int col = lane & 15;
    const int r0  = (lane >> 4) * 4;
    const float bv = bias[nt * 16 + col];
    #pragma unroll
    for (int r = 0; r < 4; ++r) {
        out[(size_t)(mt * 16 + r0 + r) * OUTn + nt * 16 + col] = acc[r] + bv;
    }
}

extern "C" void kernel_launch(void* const* d_in, const int* in_sizes, int n_in,
                              void* d_out, int out_size, void* d_ws, size_t ws_size,
                              hipStream_t stream) {
    const float* adj  = (const float*)d_in[0];
    const float* feat = (const float*)d_in[1];
    const float* W    = (const float*)d_in[2];
    const float* bias = (const float*)d_in[3];
    float* out = (float*)d_out;

    unsigned short* comb = (unsigned short*)d_ws;          // 1 MB
    unsigned int*   flags = (unsigned int*)(comb + (size_t)NNODES * KK); // 8 KB

    sage_onepass<<<dim3(NNODES + GEMM_BLOCKS), dim3(256), 0, stream>>>(
        adj, feat, W, bias, comb, flags, out);
}